// Round 6
// baseline (2253.508 us; speedup 1.0000x reference)
//
#include <hip/hip_runtime.h>
#include <math.h>

#define N_NODES  100000
#define N_HEDGES 50000
#define N_INC    300000
#define N_GRAPHS 1024
#define D_IN     49
#define D        512
#define NPAD     100096   // 782 * 128
#define KPAD_IN  64

typedef __attribute__((ext_vector_type(8))) short short8;
typedef __attribute__((ext_vector_type(4))) float f32x4;

__device__ __forceinline__ short f2bf(float f) {
    union { float f; unsigned u; } v; v.f = f;
    unsigned r = v.u + 0x7fffu + ((v.u >> 16) & 1u);
    return (short)(r >> 16);
}
__device__ __forceinline__ float bf2f(short s) {
    union { unsigned u; float f; } v; v.u = ((unsigned)(unsigned short)s) << 16;
    return v.f;
}

// ---------------- weight pack: W[K,512] f32 -> B-fragment layout bf16 ----------------
// Bp[((c16*NK + t)*64 + l)*8 + e] = bf16(W[t*32 + (l>>4)*8 + e][c16*16 + (l&15)])
// so a wave's b-fragment load is one coalesced 16B/lane read.
__global__ void wpack_kernel(const float* __restrict__ W, short* __restrict__ Bp, int Kreal, int NK) {
    const int g = blockIdx.x;          // g = c16*NK + t
    const int t = g % NK;
    const int l = threadIdx.x;         // 64
    const int n  = ((g / NK) << 4) + (l & 15);
    const int k0 = t * 32 + (l >> 4) * 8;
    short8 o;
    #pragma unroll
    for (int e = 0; e < 8; e++) {
        int k = k0 + e;
        o[e] = (k < Kreal) ? f2bf(W[(long)k * D + n]) : (short)0;
    }
    *(short8*)(Bp + ((long)g * 64 + l) * 8) = o;
}

// ---------------- GEMM: C[M,512] = A[M,K](bf16,row-major) @ W (packed Bp) + bias (+resid_bf16) ----
// Wave-autonomous: NO LDS, NO barriers. Each wave computes a 64x64 output tile.
// A-fragments loaded directly from global (16 rows x 64B per instr, L2 lines reused across t);
// B-fragments from packed L2-resident Bp (fully coalesced). Compiler handles counted vmcnt +
// software pipelining (no barrier = no vmcnt(0) drain).
template<int NK>
__global__ __launch_bounds__(256, 3) void gemm_frag(
    const short* __restrict__ A, const short* __restrict__ Bp,
    const float* __restrict__ bias, const short* __restrict__ residbf,
    short* __restrict__ Cbf, float* __restrict__ Cf, int nby)
{
    constexpr int K = NK * 32;
    const int tid  = threadIdx.x;
    const int lane = tid & 63;
    const int wave = tid >> 6;
    const int wr = wave >> 1, wc = wave & 1;

    // bijective XCD-aware chunked swizzle (m204): consecutive wg (same row-block) -> same XCD
    const int nwg = gridDim.x;
    const int q8 = nwg >> 3, r8 = nwg & 7;
    const int xcd = blockIdx.x & 7, loc = blockIdx.x >> 3;
    const int wg = (xcd < r8) ? (xcd * (q8 + 1) + loc) : (r8 * (q8 + 1) + (xcd - r8) * q8 + loc);
    const long row0 = (long)(wg / nby) * 128;
    const int  col0 = (wg % nby) * 128;

    const int rl = lane & 15;
    const int ks = lane >> 4;

    f32x4 acc[4][4];
    #pragma unroll
    for (int m = 0; m < 4; m++)
        #pragma unroll
        for (int n = 0; n < 4; n++)
            acc[m][n] = (f32x4)(0.0f);

    const short* aBase = A + (row0 + wr * 64 + rl) * (long)K + ks * 8;
    const int c16b = (col0 >> 4) + wc * 4;
    const short* bBase = Bp + (long)c16b * NK * 512 + lane * 8;

    #pragma unroll 4
    for (int t = 0; t < NK; t++) {
        short8 a[4], b[4];
        #pragma unroll
        for (int m = 0; m < 4; m++)
            a[m] = *(const short8*)(aBase + (long)m * 16 * K + t * 32);
        #pragma unroll
        for (int n = 0; n < 4; n++)
            b[n] = *(const short8*)(bBase + (n * NK + t) * 512);
        #pragma unroll
        for (int m = 0; m < 4; m++)
            #pragma unroll
            for (int n = 0; n < 4; n++)
                asm("v_mfma_f32_16x16x32_bf16 %0, %1, %2, %0"
                    : "+v"(acc[m][n]) : "v"(a[m]), "v"(b[n]));
    }

    const int rb4 = wr * 64 + ks * 4;
    #pragma unroll
    for (int m = 0; m < 4; m++) {
        #pragma unroll
        for (int n = 0; n < 4; n++) {
            const int col = col0 + wc * 64 + n * 16 + rl;
            const float bi = bias[col];
            #pragma unroll
            for (int rr = 0; rr < 4; rr++) {
                const long row = row0 + rb4 + m * 16 + rr;
                float v = acc[m][n][rr] + bi;
                if (residbf) v += bf2f(residbf[row * D + col]);
                if (Cbf) Cbf[row * D + col] = f2bf(v);
                if (Cf)  Cf[row * D + col]  = v;
            }
        }
    }
}

// ---------------- degree counts ----------------
__global__ void count_inc_kernel(const int* __restrict__ nidx, const int* __restrict__ hidx,
                                 int* cnt_n, int* cnt_h) {
    int i = blockIdx.x * 256 + threadIdx.x;
    if (i < N_INC) {
        atomicAdd(&cnt_h[hidx[i]], 1);
        atomicAdd(&cnt_n[nidx[i]], 1);
    }
}

// single-block exclusive scan
__global__ __launch_bounds__(256) void scan_kernel(const int* __restrict__ cnt, int* __restrict__ off, int n) {
    __shared__ int sums[256];
    int t = threadIdx.x;
    int chunk = (n + 255) / 256;
    int s = t * chunk;
    int e = min(s + chunk, n);
    int loc = 0;
    for (int i = s; i < e; i++) loc += cnt[i];
    sums[t] = loc;
    __syncthreads();
    for (int ofs = 1; ofs < 256; ofs <<= 1) {
        int v = (t >= ofs) ? sums[t - ofs] : 0;
        __syncthreads();
        sums[t] += v;
        __syncthreads();
    }
    int run = (t == 0) ? 0 : sums[t - 1];
    for (int i = s; i < e; i++) { off[i] = run; run += cnt[i]; }
    if (t == 255) off[n] = run;
}

// CSR placement via atomic cursors
__global__ void place_kernel(const int* __restrict__ nidx, const int* __restrict__ hidx,
                             const int* __restrict__ hoff, const int* __restrict__ noff,
                             int* hcur, int* ncur, int* __restrict__ hlist, int* __restrict__ nlist) {
    int e = blockIdx.x * 256 + threadIdx.x;
    if (e < N_INC) {
        int h = hidx[e], n = nidx[e];
        int p = atomicAdd(&hcur[h], 1);
        hlist[hoff[h] + p] = n;
        int q = atomicAdd(&ncur[n], 1);
        nlist[noff[n] + q] = h;
    }
}

// node_features [N,49] f32 -> A0 [NPAD,64] bf16 (zero pad)
__global__ void cvt_in_kernel(const float* __restrict__ nf, short* __restrict__ A0) {
    int r = blockIdx.x;
    int c = threadIdx.x;
    short v = 0;
    if (r < N_NODES && c < D_IN) v = f2bf(nf[(long)r * D_IN + c]);
    A0[(long)r * KPAD_IN + c] = v;
}

// hedge gather + msg (bf16 in/out, f32 accum)
__global__ __launch_bounds__(256) void hedge_gather_kernel(
    const short* __restrict__ src, const int* __restrict__ hoff, const int* __restrict__ hlist,
    const int* __restrict__ htype, const float* __restrict__ temb, short* __restrict__ out)
{
    int hrow = blockIdx.x * 4 + (threadIdx.x >> 6);
    if (hrow >= N_HEDGES) return;
    int lane = threadIdx.x & 63;
    int s = hoff[hrow], e = hoff[hrow + 1];
    float acc[8] = {0, 0, 0, 0, 0, 0, 0, 0};
    for (int j = s; j < e; j++) {
        short8 v = *(const short8*)(src + (long)hlist[j] * D + lane * 8);
        #pragma unroll
        for (int k = 0; k < 8; k++) acc[k] += bf2f(v[k]);
    }
    float inv = 1.0f / fmaxf((float)(e - s), 1.0f);
    const float* tp = temb + (long)htype[hrow] * D + lane * 8;
    float4 t0 = *(const float4*)tp;
    float4 t1 = *(const float4*)(tp + 4);
    float tv[8] = {t0.x, t0.y, t0.z, t0.w, t1.x, t1.y, t1.z, t1.w};
    short8 o;
    #pragma unroll
    for (int k = 0; k < 8; k++) o[k] = f2bf(acc[k] * inv + tv[k]);
    *(short8*)(out + (long)hrow * D + lane * 8) = o;
}

// node gather (bf16 in/out)
__global__ __launch_bounds__(256) void node_gather_kernel(
    const short* __restrict__ hmsg, const int* __restrict__ noff, const int* __restrict__ nlist,
    short* __restrict__ Abf)
{
    int r = blockIdx.x * 4 + (threadIdx.x >> 6);
    if (r >= NPAD) return;
    int lane = threadIdx.x & 63;
    short8 o = (short8)0;
    if (r < N_NODES) {
        int s = noff[r], e = noff[r + 1];
        float acc[8] = {0, 0, 0, 0, 0, 0, 0, 0};
        for (int j = s; j < e; j++) {
            short8 v = *(const short8*)(hmsg + (long)nlist[j] * D + lane * 8);
            #pragma unroll
            for (int k = 0; k < 8; k++) acc[k] += bf2f(v[k]);
        }
        float inv = 1.0f / fmaxf((float)(e - s), 1.0f);
        #pragma unroll
        for (int k = 0; k < 8; k++) o[k] = f2bf(acc[k] * inv);
    }
    *(short8*)(Abf + (long)r * D + lane * 8) = o;
}

// LayerNorm + exact GELU, one wave per row; bf16 in, bf16 out (+opt f32)
__global__ __launch_bounds__(256) void ln_gelu_kernel(
    const short* __restrict__ in, short* __restrict__ outbf, float* __restrict__ outf,
    const float* __restrict__ g, const float* __restrict__ b)
{
    const int row = blockIdx.x * 4 + (threadIdx.x >> 6);
    const int lane = threadIdx.x & 63;
    short8 v = *(const short8*)(in + (long)row * D + lane * 8);
    float f[8];
    float s = 0.f, q = 0.f;
    #pragma unroll
    for (int j = 0; j < 8; j++) { f[j] = bf2f(v[j]); s += f[j]; q += f[j] * f[j]; }
    #pragma unroll
    for (int o = 32; o > 0; o >>= 1) { s += __shfl_xor(s, o, 64); q += __shfl_xor(q, o, 64); }
    const float mean = s * (1.0f / D);
    const float var  = q * (1.0f / D) - mean * mean;
    const float rstd = rsqrtf(var + 1e-5f);
    const float4 g0 = *(const float4*)(g + lane * 8);
    const float4 g1 = *(const float4*)(g + lane * 8 + 4);
    const float4 b0 = *(const float4*)(b + lane * 8);
    const float4 b1 = *(const float4*)(b + lane * 8 + 4);
    const float gv[8] = {g0.x, g0.y, g0.z, g0.w, g1.x, g1.y, g1.z, g1.w};
    const float bv[8] = {b0.x, b0.y, b0.z, b0.w, b1.x, b1.y, b1.z, b1.w};
    float yout[8];
    short8 o8;
    #pragma unroll
    for (int j = 0; j < 8; j++) {
        float y = (f[j] - mean) * rstd * gv[j] + bv[j];
        float gl = 0.5f * y * (1.0f + erff(y * 0.70710678118654752f));
        yout[j] = gl;
        o8[j] = f2bf(gl);
    }
    *(short8*)(outbf + (long)row * D + lane * 8) = o8;
    if (outf) {
        float4 o0 = {yout[0], yout[1], yout[2], yout[3]};
        float4 o1 = {yout[4], yout[5], yout[6], yout[7]};
        *(float4*)(outf + (long)row * D + lane * 8) = o0;
        *(float4*)(outf + (long)row * D + lane * 8 + 4) = o1;
    }
}

// graph pooling via sorted batch segments (bf16 in)
__global__ __launch_bounds__(64) void pool_kernel(const short* __restrict__ x, const int* __restrict__ batch,
                                                  short* __restrict__ Gbf) {
    int g = blockIdx.x;
    int lo = 0, hi = N_NODES;
    while (lo < hi) { int mid = (lo + hi) >> 1; if (batch[mid] < g) lo = mid + 1; else hi = mid; }
    int s = lo;
    hi = N_NODES;
    while (lo < hi) { int mid = (lo + hi) >> 1; if (batch[mid] < g + 1) lo = mid + 1; else hi = mid; }
    int e = lo;
    int lane = threadIdx.x;
    float acc[8] = {0, 0, 0, 0, 0, 0, 0, 0};
    for (int r = s; r < e; r++) {
        short8 v = *(const short8*)(x + (long)r * D + lane * 8);
        #pragma unroll
        for (int k = 0; k < 8; k++) acc[k] += bf2f(v[k]);
    }
    float inv = 1.0f / fmaxf((float)(e - s), 1.0f);
    short8 o;
    #pragma unroll
    for (int k = 0; k < 8; k++) o[k] = f2bf(acc[k] * inv);
    *(short8*)(Gbf + (long)g * D + lane * 8) = o;
}

__global__ void batchf_kernel(const int* __restrict__ batch, float* __restrict__ ob) {
    int i = blockIdx.x * 256 + threadIdx.x;
    if (i < N_NODES) ob[i] = (float)batch[i];
}

extern "C" void kernel_launch(void* const* d_in, const int* in_sizes, int n_in,
                              void* d_out, int out_size, void* d_ws, size_t ws_size,
                              hipStream_t stream) {
    (void)in_sizes; (void)n_in; (void)out_size; (void)ws_size;
    const float* nf    = (const float*)d_in[0];
    const int*   nidx  = (const int*)d_in[1];
    const int*   hidx  = (const int*)d_in[2];
    const int*   htype = (const int*)d_in[3];
    const int*   batch = (const int*)d_in[4];
    const float* in_w  = (const float*)d_in[6];
    const float* in_b  = (const float*)d_in[7];
    const float* temb  = (const float*)d_in[8];
    const float* l1w   = (const float*)d_in[9];
    const float* l1b   = (const float*)d_in[10];
    const float* l2w   = (const float*)d_in[11];
    const float* l2b   = (const float*)d_in[12];
    const float* lng   = (const float*)d_in[13];
    const float* lnb   = (const float*)d_in[14];
    const float* outw  = (const float*)d_in[15];
    const float* outb  = (const float*)d_in[16];

    float* out_graph = (float*)d_out;                       // [1024,512]
    float* out_nodes = out_graph + (long)N_GRAPHS * D;      // [100000,512]
    float* out_batch = out_nodes + (long)N_NODES * D;       // [100000]

    char* wsb = (char*)d_ws;
    size_t off = 0;
    auto alloc = [&](size_t bytes) {
        void* p = wsb + off;
        off += (bytes + 255) & ~(size_t)255;
        return p;
    };
    short* x_bf  = (short*)alloc((size_t)NPAD * D * 2);
    short* t1_bf = (short*)alloc((size_t)NPAD * D * 2);
    short* A_bf  = (short*)alloc((size_t)NPAD * D * 2);
    short* h_bf  = (short*)alloc((size_t)N_HEDGES * D * 2);
    short* G_bf  = (short*)alloc((size_t)N_GRAPHS * D * 2);
    short* A0    = (short*)alloc((size_t)NPAD * KPAD_IN * 2);
    short* wt    = (short*)alloc((size_t)D * D * 2);
    int* cnt_h   = (int*)alloc((size_t)N_HEDGES * 4);
    int* cnt_n   = (int*)alloc((size_t)N_NODES * 4);
    int* hoff    = (int*)alloc((size_t)(N_HEDGES + 1) * 4);
    int* noff    = (int*)alloc((size_t)(N_NODES + 1) * 4);
    int* hcur    = (int*)alloc((size_t)N_HEDGES * 4);
    int* ncur    = (int*)alloc((size_t)N_NODES * 4);
    int* hlist   = (int*)alloc((size_t)N_INC * 4);
    int* nlist   = (int*)alloc((size_t)N_INC * 4);

    // ---- build CSR (both directions) ----
    hipMemsetAsync(cnt_h, 0, (size_t)N_HEDGES * 4, stream);
    hipMemsetAsync(cnt_n, 0, (size_t)N_NODES * 4, stream);
    hipMemsetAsync(hcur,  0, (size_t)N_HEDGES * 4, stream);
    hipMemsetAsync(ncur,  0, (size_t)N_NODES * 4, stream);
    count_inc_kernel<<<(N_INC + 255) / 256, 256, 0, stream>>>(nidx, hidx, cnt_n, cnt_h);
    scan_kernel<<<1, 256, 0, stream>>>(cnt_h, hoff, N_HEDGES);
    scan_kernel<<<1, 256, 0, stream>>>(cnt_n, noff, N_NODES);
    place_kernel<<<(N_INC + 255) / 256, 256, 0, stream>>>(nidx, hidx, hoff, noff, hcur, ncur, hlist, nlist);
    batchf_kernel<<<(N_NODES + 255) / 256, 256, 0, stream>>>(batch, out_batch);

    // ---- input projection: x_bf = bf16(nf @ in_w + in_b) ----
    wpack_kernel<<<32 * 2, 64, 0, stream>>>(in_w, wt, D_IN, 2);
    cvt_in_kernel<<<NPAD, 64, 0, stream>>>(nf, A0);
    const int NWG = (NPAD / 128) * 4;   // 3128
    gemm_frag<2><<<NWG, 256, 0, stream>>>(A0, wt, in_b, nullptr, x_bf, nullptr, 4);

    for (int i = 0; i < 3; i++) {
        // t1 = x @ l1_w[i] + l1_b[i]
        wpack_kernel<<<32 * 16, 64, 0, stream>>>(l1w + (size_t)i * D * D, wt, D, 16);
        gemm_frag<16><<<NWG, 256, 0, stream>>>(x_bf, wt, l1b + i * D, nullptr, t1_bf, nullptr, 4);
        // hedge aggregate + msg
        hedge_gather_kernel<<<(N_HEDGES + 3) / 4, 256, 0, stream>>>(t1_bf, hoff, hlist, htype, temb, h_bf);
        // node aggregate
        node_gather_kernel<<<NPAD / 4, 256, 0, stream>>>(h_bf, noff, nlist, A_bf);
        // y = x + node_aggr @ l2_w[i] + l2_b[i]
        wpack_kernel<<<32 * 16, 64, 0, stream>>>(l2w + (size_t)i * D * D, wt, D, 16);
        gemm_frag<16><<<NWG, 256, 0, stream>>>(A_bf, wt, l2b + i * D, x_bf, t1_bf, nullptr, 4);
        // x = gelu(ln(y));  final layer also writes f32 out_nodes
        ln_gelu_kernel<<<N_NODES / 4, 256, 0, stream>>>(t1_bf, x_bf, (i < 2) ? nullptr : out_nodes,
                                                        lng + i * D, lnb + i * D);
    }

    // ---- graph pooling + output projection ----
    pool_kernel<<<N_GRAPHS, 64, 0, stream>>>(x_bf, batch, G_bf);
    wpack_kernel<<<32 * 16, 64, 0, stream>>>(outw, wt, D, 16);
    gemm_frag<16><<<(N_GRAPHS / 128) * 4, 256, 0, stream>>>(G_bf, wt, outb, nullptr, nullptr, out_graph, 4);
}

// Round 7
// 1914.193 us; speedup vs baseline: 1.1773x; 1.1773x over previous
//
#include <hip/hip_runtime.h>
#include <math.h>

#define N_NODES  100000
#define N_HEDGES 50000
#define N_INC    300000
#define N_GRAPHS 1024
#define D_IN     49
#define D        512
#define NPAD     100096   // 782 * 128
#define KPAD_IN  64

typedef __attribute__((ext_vector_type(8))) short short8;
typedef __attribute__((ext_vector_type(8))) __bf16 bf16x8;
typedef __attribute__((ext_vector_type(4))) float f32x4;

__device__ __forceinline__ short f2bf(float f) {
    union { float f; unsigned u; } v; v.f = f;
    unsigned r = v.u + 0x7fffu + ((v.u >> 16) & 1u);
    return (short)(r >> 16);
}
__device__ __forceinline__ float bf2f(short s) {
    union { unsigned u; float f; } v; v.u = ((unsigned)(unsigned short)s) << 16;
    return v.f;
}

__device__ __forceinline__ void gld16(const void* g, void* l) {
    __builtin_amdgcn_global_load_lds(
        (const __attribute__((address_space(1))) unsigned int*)g,
        (__attribute__((address_space(3))) unsigned int*)l, 16, 0, 0);
}

// ---------------- GEMM: C[M,512] = A[M,K](bf16) @ Bt[512,K](bf16) + bias (+resid_bf16) ----------------
// 128x128 tile, 4 waves (2x2). global_load_lds(16B) staging with pre-swizzled source
// (conflict-free ds_read_b128). Double-buffered, ONE __syncthreads per 32-K step.
// MFMA via BUILTIN (not inline asm) so LLVM can model latency, pipeline, and use AGPRs.
__global__ __launch_bounds__(256) void gemm_bf16(
    const short* __restrict__ A, const short* __restrict__ Bt,
    const float* __restrict__ bias, const short* __restrict__ residbf,
    short* __restrict__ Cbf, float* __restrict__ Cf, int K, int nby)
{
    __shared__ short As[2][128][32];
    __shared__ short Bs[2][128][32];
    const int tid  = threadIdx.x;
    const int lane = tid & 63;
    const int wave = tid >> 6;
    const int wr = wave >> 1, wc = wave & 1;

    // bijective XCD-aware swizzle (m204)
    const int nwg = gridDim.x;
    const int q8 = nwg >> 3, r8 = nwg & 7;
    const int xcd = blockIdx.x & 7, loc = blockIdx.x >> 3;
    const int wg = (xcd < r8) ? (xcd * (q8 + 1) + loc) : (r8 * (q8 + 1) + (xcd - r8) * q8 + loc);
    const long row0 = (long)(wg / nby) * 128;
    const int  col0 = (wg % nby) * 128;

    f32x4 acc[4][4];
    #pragma unroll
    for (int m = 0; m < 4; m++)
        #pragma unroll
        for (int n = 0; n < 4; n++)
            acc[m][n] = (f32x4)(0.0f);

    // staging: instr q (= wave*2+j) covers LDS rows q*16..q*16+15; lane l -> row q*16+l/4, chunk l%4.
    // LDS (row,c) holds global chunk c ^ sw(row), sw=(row>>1)&3 (pre-swizzled source address).
    const int ch   = lane & 3;
    const int rofs = lane >> 2;
    const short* aSrc[2];
    const short* bSrc[2];
    #pragma unroll
    for (int j = 0; j < 2; j++) {
        const int q = wave * 2 + j;
        const int rloc = q * 16 + rofs;
        const int sw = (rloc >> 1) & 3;
        aSrc[j] = A  + (row0 + rloc) * (long)K + (ch ^ sw) * 8;
        bSrc[j] = Bt + ((long)col0 + rloc) * K + (ch ^ sw) * 8;
    }

    const int ks = lane >> 4;
    const int rl = lane & 15;
    const int nk = K >> 5;

    // prologue: stage tile 0 into buf 0
    #pragma unroll
    for (int j = 0; j < 2; j++) {
        const int q = wave * 2 + j;
        gld16(aSrc[j], &As[0][q * 16][0]);
        gld16(bSrc[j], &Bs[0][q * 16][0]);
    }
    __syncthreads();

    int cur = 0;
    for (int t = 0; t < nk; t++) {
        if (t + 1 < nk) {                     // stage next tile into other buffer (in flight across MFMA)
            const int nxt = cur ^ 1;
            #pragma unroll
            for (int j = 0; j < 2; j++) {
                const int q = wave * 2 + j;
                gld16(aSrc[j] + (t + 1) * 32, &As[nxt][q * 16][0]);
                gld16(bSrc[j] + (t + 1) * 32, &Bs[nxt][q * 16][0]);
            }
        }
        bf16x8 a[4], b[4];
        #pragma unroll
        for (int m = 0; m < 4; m++) {
            const int rr = wr * 64 + m * 16 + rl;
            a[m] = *(const bf16x8*)&As[cur][rr][(ks ^ ((rr >> 1) & 3)) * 8];
        }
        #pragma unroll
        for (int n = 0; n < 4; n++) {
            const int rr = wc * 64 + n * 16 + rl;
            b[n] = *(const bf16x8*)&Bs[cur][rr][(ks ^ ((rr >> 1) & 3)) * 8];
        }
        #pragma unroll
        for (int m = 0; m < 4; m++)
            #pragma unroll
            for (int n = 0; n < 4; n++)
                acc[m][n] = __builtin_amdgcn_mfma_f32_16x16x32_bf16(a[m], b[n], acc[m][n], 0, 0, 0);
        __syncthreads();                      // drains stage loads; readers done; swap
        cur ^= 1;
    }

    const int rl2 = lane & 15;
    const int rb4 = wr * 64 + (lane >> 4) * 4;
    #pragma unroll
    for (int m = 0; m < 4; m++) {
        #pragma unroll
        for (int n = 0; n < 4; n++) {
            const int col = col0 + wc * 64 + n * 16 + rl2;
            const float bi = bias[col];
            #pragma unroll
            for (int rr = 0; rr < 4; rr++) {
                const long row = row0 + rb4 + m * 16 + rr;
                float v = acc[m][n][rr] + bi;
                if (residbf) v += bf2f(residbf[row * D + col]);
                if (Cbf) Cbf[row * D + col] = f2bf(v);
                if (Cf)  Cf[row * D + col]  = v;
            }
        }
    }
}

// ---------------- degree counts ----------------
__global__ void count_inc_kernel(const int* __restrict__ nidx, const int* __restrict__ hidx,
                                 int* cnt_n, int* cnt_h) {
    int i = blockIdx.x * 256 + threadIdx.x;
    if (i < N_INC) {
        atomicAdd(&cnt_h[hidx[i]], 1);
        atomicAdd(&cnt_n[nidx[i]], 1);
    }
}

// single-block exclusive scan
__global__ __launch_bounds__(256) void scan_kernel(const int* __restrict__ cnt, int* __restrict__ off, int n) {
    __shared__ int sums[256];
    int t = threadIdx.x;
    int chunk = (n + 255) / 256;
    int s = t * chunk;
    int e = min(s + chunk, n);
    int loc = 0;
    for (int i = s; i < e; i++) loc += cnt[i];
    sums[t] = loc;
    __syncthreads();
    for (int ofs = 1; ofs < 256; ofs <<= 1) {
        int v = (t >= ofs) ? sums[t - ofs] : 0;
        __syncthreads();
        sums[t] += v;
        __syncthreads();
    }
    int run = (t == 0) ? 0 : sums[t - 1];
    for (int i = s; i < e; i++) { off[i] = run; run += cnt[i]; }
    if (t == 255) off[n] = run;
}

// CSR placement via atomic cursors
__global__ void place_kernel(const int* __restrict__ nidx, const int* __restrict__ hidx,
                             const int* __restrict__ hoff, const int* __restrict__ noff,
                             int* hcur, int* ncur, int* __restrict__ hlist, int* __restrict__ nlist) {
    int e = blockIdx.x * 256 + threadIdx.x;
    if (e < N_INC) {
        int h = hidx[e], n = nidx[e];
        int p = atomicAdd(&hcur[h], 1);
        hlist[hoff[h] + p] = n;
        int q = atomicAdd(&ncur[n], 1);
        nlist[noff[n] + q] = h;
    }
}

// ---------------- weight transpose+convert: W[K,512] f32 -> Wt[512,Kpad] bf16 ----------------
__global__ void wtrans_kernel(const float* __restrict__ W, short* __restrict__ Wt, int K, int Kpad) {
    int n = blockIdx.x;
    for (int k = threadIdx.x; k < Kpad; k += 64)
        Wt[(long)n * Kpad + k] = (k < K) ? f2bf(W[(long)k * D + n]) : (short)0;
}

// node_features [N,49] f32 -> A0 [NPAD,64] bf16 (zero pad)
__global__ void cvt_in_kernel(const float* __restrict__ nf, short* __restrict__ A0) {
    int r = blockIdx.x;
    int c = threadIdx.x;
    short v = 0;
    if (r < N_NODES && c < D_IN) v = f2bf(nf[(long)r * D_IN + c]);
    A0[(long)r * KPAD_IN + c] = v;
}

// hedge gather + msg (bf16 in/out, f32 accum)
__global__ __launch_bounds__(256) void hedge_gather_kernel(
    const short* __restrict__ src, const int* __restrict__ hoff, const int* __restrict__ hlist,
    const int* __restrict__ htype, const float* __restrict__ temb, short* __restrict__ out)
{
    int hrow = blockIdx.x * 4 + (threadIdx.x >> 6);
    if (hrow >= N_HEDGES) return;
    int lane = threadIdx.x & 63;
    int s = hoff[hrow], e = hoff[hrow + 1];
    float acc[8] = {0, 0, 0, 0, 0, 0, 0, 0};
    for (int j = s; j < e; j++) {
        short8 v = *(const short8*)(src + (long)hlist[j] * D + lane * 8);
        #pragma unroll
        for (int k = 0; k < 8; k++) acc[k] += bf2f(v[k]);
    }
    float inv = 1.0f / fmaxf((float)(e - s), 1.0f);
    const float* tp = temb + (long)htype[hrow] * D + lane * 8;
    float4 t0 = *(const float4*)tp;
    float4 t1 = *(const float4*)(tp + 4);
    float tv[8] = {t0.x, t0.y, t0.z, t0.w, t1.x, t1.y, t1.z, t1.w};
    short8 o;
    #pragma unroll
    for (int k = 0; k < 8; k++) o[k] = f2bf(acc[k] * inv + tv[k]);
    *(short8*)(out + (long)hrow * D + lane * 8) = o;
}

// node gather (bf16 in/out)
__global__ __launch_bounds__(256) void node_gather_kernel(
    const short* __restrict__ hmsg, const int* __restrict__ noff, const int* __restrict__ nlist,
    short* __restrict__ Abf)
{
    int r = blockIdx.x * 4 + (threadIdx.x >> 6);
    if (r >= NPAD) return;
    int lane = threadIdx.x & 63;
    short8 o = (short8)0;
    if (r < N_NODES) {
        int s = noff[r], e = noff[r + 1];
        float acc[8] = {0, 0, 0, 0, 0, 0, 0, 0};
        for (int j = s; j < e; j++) {
            short8 v = *(const short8*)(hmsg + (long)nlist[j] * D + lane * 8);
            #pragma unroll
            for (int k = 0; k < 8; k++) acc[k] += bf2f(v[k]);
        }
        float inv = 1.0f / fmaxf((float)(e - s), 1.0f);
        #pragma unroll
        for (int k = 0; k < 8; k++) o[k] = f2bf(acc[k] * inv);
    }
    *(short8*)(Abf + (long)r * D + lane * 8) = o;
}

// LayerNorm + exact GELU, one wave per row; bf16 in, bf16 out (+opt f32)
__global__ __launch_bounds__(256) void ln_gelu_kernel(
    const short* __restrict__ in, short* __restrict__ outbf, float* __restrict__ outf,
    const float* __restrict__ g, const float* __restrict__ b)
{
    const int row = blockIdx.x * 4 + (threadIdx.x >> 6);
    const int lane = threadIdx.x & 63;
    short8 v = *(const short8*)(in + (long)row * D + lane * 8);
    float f[8];
    float s = 0.f, q = 0.f;
    #pragma unroll
    for (int j = 0; j < 8; j++) { f[j] = bf2f(v[j]); s += f[j]; q += f[j] * f[j]; }
    #pragma unroll
    for (int o = 32; o > 0; o >>= 1) { s += __shfl_xor(s, o, 64); q += __shfl_xor(q, o, 64); }
    const float mean = s * (1.0f / D);
    const float var  = q * (1.0f / D) - mean * mean;
    const float rstd = rsqrtf(var + 1e-5f);
    const float4 g0 = *(const float4*)(g + lane * 8);
    const float4 g1 = *(const float4*)(g + lane * 8 + 4);
    const float4 b0 = *(const float4*)(b + lane * 8);
    const float4 b1 = *(const float4*)(b + lane * 8 + 4);
    const float gv[8] = {g0.x, g0.y, g0.z, g0.w, g1.x, g1.y, g1.z, g1.w};
    const float bv[8] = {b0.x, b0.y, b0.z, b0.w, b1.x, b1.y, b1.z, b1.w};
    float yout[8];
    short8 o8;
    #pragma unroll
    for (int j = 0; j < 8; j++) {
        float y = (f[j] - mean) * rstd * gv[j] + bv[j];
        float gl = 0.5f * y * (1.0f + erff(y * 0.70710678118654752f));
        yout[j] = gl;
        o8[j] = f2bf(gl);
    }
    *(short8*)(outbf + (long)row * D + lane * 8) = o8;
    if (outf) {
        float4 o0 = {yout[0], yout[1], yout[2], yout[3]};
        float4 o1 = {yout[4], yout[5], yout[6], yout[7]};
        *(float4*)(outf + (long)row * D + lane * 8) = o0;
        *(float4*)(outf + (long)row * D + lane * 8 + 4) = o1;
    }
}

// graph pooling via sorted batch segments (bf16 in)
__global__ __launch_bounds__(64) void pool_kernel(const short* __restrict__ x, const int* __restrict__ batch,
                                                  short* __restrict__ Gbf) {
    int g = blockIdx.x;
    int lo = 0, hi = N_NODES;
    while (lo < hi) { int mid = (lo + hi) >> 1; if (batch[mid] < g) lo = mid + 1; else hi = mid; }
    int s = lo;
    hi = N_NODES;
    while (lo < hi) { int mid = (lo + hi) >> 1; if (batch[mid] < g + 1) lo = mid + 1; else hi = mid; }
    int e = lo;
    int lane = threadIdx.x;
    float acc[8] = {0, 0, 0, 0, 0, 0, 0, 0};
    for (int r = s; r < e; r++) {
        short8 v = *(const short8*)(x + (long)r * D + lane * 8);
        #pragma unroll
        for (int k = 0; k < 8; k++) acc[k] += bf2f(v[k]);
    }
    float inv = 1.0f / fmaxf((float)(e - s), 1.0f);
    short8 o;
    #pragma unroll
    for (int k = 0; k < 8; k++) o[k] = f2bf(acc[k] * inv);
    *(short8*)(Gbf + (long)g * D + lane * 8) = o;
}

__global__ void batchf_kernel(const int* __restrict__ batch, float* __restrict__ ob) {
    int i = blockIdx.x * 256 + threadIdx.x;
    if (i < N_NODES) ob[i] = (float)batch[i];
}

extern "C" void kernel_launch(void* const* d_in, const int* in_sizes, int n_in,
                              void* d_out, int out_size, void* d_ws, size_t ws_size,
                              hipStream_t stream) {
    (void)in_sizes; (void)n_in; (void)out_size; (void)ws_size;
    const float* nf    = (const float*)d_in[0];
    const int*   nidx  = (const int*)d_in[1];
    const int*   hidx  = (const int*)d_in[2];
    const int*   htype = (const int*)d_in[3];
    const int*   batch = (const int*)d_in[4];
    const float* in_w  = (const float*)d_in[6];
    const float* in_b  = (const float*)d_in[7];
    const float* temb  = (const float*)d_in[8];
    const float* l1w   = (const float*)d_in[9];
    const float* l1b   = (const float*)d_in[10];
    const float* l2w   = (const float*)d_in[11];
    const float* l2b   = (const float*)d_in[12];
    const float* lng   = (const float*)d_in[13];
    const float* lnb   = (const float*)d_in[14];
    const float* outw  = (const float*)d_in[15];
    const float* outb  = (const float*)d_in[16];

    float* out_graph = (float*)d_out;                       // [1024,512]
    float* out_nodes = out_graph + (long)N_GRAPHS * D;      // [100000,512]
    float* out_batch = out_nodes + (long)N_NODES * D;       // [100000]

    char* wsb = (char*)d_ws;
    size_t off = 0;
    auto alloc = [&](size_t bytes) {
        void* p = wsb + off;
        off += (bytes + 255) & ~(size_t)255;
        return p;
    };
    short* x_bf  = (short*)alloc((size_t)NPAD * D * 2);
    short* t1_bf = (short*)alloc((size_t)NPAD * D * 2);
    short* A_bf  = (short*)alloc((size_t)NPAD * D * 2);
    short* h_bf  = (short*)alloc((size_t)N_HEDGES * D * 2);
    short* G_bf  = (short*)alloc((size_t)N_GRAPHS * D * 2);
    short* A0    = (short*)alloc((size_t)NPAD * KPAD_IN * 2);
    short* wt    = (short*)alloc((size_t)D * D * 2);
    int* cnt_h   = (int*)alloc((size_t)N_HEDGES * 4);
    int* cnt_n   = (int*)alloc((size_t)N_NODES * 4);
    int* hoff    = (int*)alloc((size_t)(N_HEDGES + 1) * 4);
    int* noff    = (int*)alloc((size_t)(N_NODES + 1) * 4);
    int* hcur    = (int*)alloc((size_t)N_HEDGES * 4);
    int* ncur    = (int*)alloc((size_t)N_NODES * 4);
    int* hlist   = (int*)alloc((size_t)N_INC * 4);
    int* nlist   = (int*)alloc((size_t)N_INC * 4);

    // ---- build CSR (both directions) ----
    hipMemsetAsync(cnt_h, 0, (size_t)N_HEDGES * 4, stream);
    hipMemsetAsync(cnt_n, 0, (size_t)N_NODES * 4, stream);
    hipMemsetAsync(hcur,  0, (size_t)N_HEDGES * 4, stream);
    hipMemsetAsync(ncur,  0, (size_t)N_NODES * 4, stream);
    count_inc_kernel<<<(N_INC + 255) / 256, 256, 0, stream>>>(nidx, hidx, cnt_n, cnt_h);
    scan_kernel<<<1, 256, 0, stream>>>(cnt_h, hoff, N_HEDGES);
    scan_kernel<<<1, 256, 0, stream>>>(cnt_n, noff, N_NODES);
    place_kernel<<<(N_INC + 255) / 256, 256, 0, stream>>>(nidx, hidx, hoff, noff, hcur, ncur, hlist, nlist);
    batchf_kernel<<<(N_NODES + 255) / 256, 256, 0, stream>>>(batch, out_batch);

    // ---- input projection: x_bf = bf16(nf @ in_w + in_b) ----
    wtrans_kernel<<<D, 64, 0, stream>>>(in_w, wt, D_IN, KPAD_IN);
    cvt_in_kernel<<<NPAD, 64, 0, stream>>>(nf, A0);
    const int NWG = (NPAD / 128) * 4;   // 3128
    gemm_bf16<<<NWG, 256, 0, stream>>>(A0, wt, in_b, nullptr, x_bf, nullptr, KPAD_IN, 4);

    for (int i = 0; i < 3; i++) {
        // t1 = x @ l1_w[i] + l1_b[i]
        wtrans_kernel<<<D, 64, 0, stream>>>(l1w + (size_t)i * D * D, wt, D, D);
        gemm_bf16<<<NWG, 256, 0, stream>>>(x_bf, wt, l1b + i * D, nullptr, t1_bf, nullptr, D, 4);
        // hedge aggregate + msg
        hedge_gather_kernel<<<(N_HEDGES + 3) / 4, 256, 0, stream>>>(t1_bf, hoff, hlist, htype, temb, h_bf);
        // node aggregate
        node_gather_kernel<<<NPAD / 4, 256, 0, stream>>>(h_bf, noff, nlist, A_bf);
        // y = x + node_aggr @ l2_w[i] + l2_b[i]
        wtrans_kernel<<<D, 64, 0, stream>>>(l2w + (size_t)i * D * D, wt, D, D);
        gemm_bf16<<<NWG, 256, 0, stream>>>(A_bf, wt, l2b + i * D, x_bf, t1_bf, nullptr, D, 4);
        // x = gelu(ln(y));  final layer also writes f32 out_nodes
        ln_gelu_kernel<<<N_NODES / 4, 256, 0, stream>>>(t1_bf, x_bf, (i < 2) ? nullptr : out_nodes,
                                                        lng + i * D, lnb + i * D);
    }

    // ---- graph pooling + output projection ----
    pool_kernel<<<N_GRAPHS, 64, 0, stream>>>(x_bf, batch, G_bf);
    wtrans_kernel<<<D, 64, 0, stream>>>(outw, wt, D, D);
    gemm_bf16<<<(N_GRAPHS / 128) * 4, 256, 0, stream>>>(G_bf, wt, outb, nullptr, nullptr, out_graph, D, 4);
}

// Round 8
// 1360.621 us; speedup vs baseline: 1.6562x; 1.4069x over previous
//
#include <hip/hip_runtime.h>
#include <math.h>

#define N_NODES  100000
#define N_HEDGES 50000
#define N_INC    300000
#define N_GRAPHS 1024
#define D_IN     49
#define D        512
#define NPAD     100096   // 782 * 128
#define KPAD_IN  64

typedef __attribute__((ext_vector_type(8))) short short8;
typedef __attribute__((ext_vector_type(8))) __bf16 bf16x8;
typedef __attribute__((ext_vector_type(4))) float f32x4;

__device__ __forceinline__ short f2bf(float f) {
    union { float f; unsigned u; } v; v.f = f;
    unsigned r = v.u + 0x7fffu + ((v.u >> 16) & 1u);
    return (short)(r >> 16);
}
__device__ __forceinline__ float bf2f(short s) {
    union { unsigned u; float f; } v; v.u = ((unsigned)(unsigned short)s) << 16;
    return v.f;
}

__device__ __forceinline__ void gld16(const void* g, void* l) {
    __builtin_amdgcn_global_load_lds(
        (const __attribute__((address_space(1))) unsigned int*)g,
        (__attribute__((address_space(3))) unsigned int*)l, 16, 0, 0);
}

// ---------------- GEMM: C[M,512] = A[M,K](bf16) @ Bt[512,K](bf16) (+bias) (+resid_bf16) --------------
// 128x128 tile, 4 waves. global_load_lds(16B) staging, pre-swizzled source (conflict-free ds_read).
// Double-buffered, one __syncthreads per 32-K step. Builtin MFMA.
// Outputs: Cbf (bf16 row-major), Cf (f32 row-major), CbfT (bf16 TRANSPOSED, stride 512 — for W12 pack).
__global__ __launch_bounds__(256) void gemm_bf16(
    const short* __restrict__ A, const short* __restrict__ Bt,
    const float* __restrict__ bias, const short* __restrict__ residbf,
    short* __restrict__ Cbf, float* __restrict__ Cf, short* __restrict__ CbfT, int K, int nby)
{
    __shared__ short As[2][128][32];
    __shared__ short Bs[2][128][32];
    const int tid  = threadIdx.x;
    const int lane = tid & 63;
    const int wave = tid >> 6;
    const int wr = wave >> 1, wc = wave & 1;

    // bijective XCD-aware swizzle (m204)
    const int nwg = gridDim.x;
    const int q8 = nwg >> 3, r8 = nwg & 7;
    const int xcd = blockIdx.x & 7, loc = blockIdx.x >> 3;
    const int wg = (xcd < r8) ? (xcd * (q8 + 1) + loc) : (r8 * (q8 + 1) + (xcd - r8) * q8 + loc);
    const long row0 = (long)(wg / nby) * 128;
    const int  col0 = (wg % nby) * 128;

    f32x4 acc[4][4];
    #pragma unroll
    for (int m = 0; m < 4; m++)
        #pragma unroll
        for (int n = 0; n < 4; n++)
            acc[m][n] = (f32x4)(0.0f);

    const int ch   = lane & 3;
    const int rofs = lane >> 2;
    const short* aSrc[2];
    const short* bSrc[2];
    #pragma unroll
    for (int j = 0; j < 2; j++) {
        const int q = wave * 2 + j;
        const int rloc = q * 16 + rofs;
        const int sw = (rloc >> 1) & 3;
        aSrc[j] = A  + (row0 + rloc) * (long)K + (ch ^ sw) * 8;
        bSrc[j] = Bt + ((long)col0 + rloc) * K + (ch ^ sw) * 8;
    }

    const int ks = lane >> 4;
    const int rl = lane & 15;
    const int nk = K >> 5;

    #pragma unroll
    for (int j = 0; j < 2; j++) {
        const int q = wave * 2 + j;
        gld16(aSrc[j], &As[0][q * 16][0]);
        gld16(bSrc[j], &Bs[0][q * 16][0]);
    }
    __syncthreads();

    int cur = 0;
    for (int t = 0; t < nk; t++) {
        if (t + 1 < nk) {
            const int nxt = cur ^ 1;
            #pragma unroll
            for (int j = 0; j < 2; j++) {
                const int q = wave * 2 + j;
                gld16(aSrc[j] + (t + 1) * 32, &As[nxt][q * 16][0]);
                gld16(bSrc[j] + (t + 1) * 32, &Bs[nxt][q * 16][0]);
            }
        }
        bf16x8 a[4], b[4];
        #pragma unroll
        for (int m = 0; m < 4; m++) {
            const int rr = wr * 64 + m * 16 + rl;
            a[m] = *(const bf16x8*)&As[cur][rr][(ks ^ ((rr >> 1) & 3)) * 8];
        }
        #pragma unroll
        for (int n = 0; n < 4; n++) {
            const int rr = wc * 64 + n * 16 + rl;
            b[n] = *(const bf16x8*)&Bs[cur][rr][(ks ^ ((rr >> 1) & 3)) * 8];
        }
        #pragma unroll
        for (int m = 0; m < 4; m++)
            #pragma unroll
            for (int n = 0; n < 4; n++)
                acc[m][n] = __builtin_amdgcn_mfma_f32_16x16x32_bf16(a[m], b[n], acc[m][n], 0, 0, 0);
        __syncthreads();
        cur ^= 1;
    }

    const int rl2 = lane & 15;
    const int rb4 = wr * 64 + (lane >> 4) * 4;
    #pragma unroll
    for (int m = 0; m < 4; m++) {
        #pragma unroll
        for (int n = 0; n < 4; n++) {
            const int col = col0 + wc * 64 + n * 16 + rl2;
            const float bi = bias ? bias[col] : 0.0f;
            #pragma unroll
            for (int rr = 0; rr < 4; rr++) {
                const long row = row0 + rb4 + m * 16 + rr;
                float v = acc[m][n][rr] + bi;
                if (residbf) v += bf2f(residbf[row * D + col]);
                if (Cbf)  Cbf[row * D + col] = f2bf(v);
                if (Cf)   Cf[row * D + col]  = v;
                if (CbfT) CbfT[(long)col * 512 + row] = f2bf(v);
            }
        }
    }
}

// ---------------- degree counts ----------------
__global__ void count_inc_kernel(const int* __restrict__ nidx, const int* __restrict__ hidx,
                                 int* cnt_n, int* cnt_h) {
    int i = blockIdx.x * 256 + threadIdx.x;
    if (i < N_INC) {
        atomicAdd(&cnt_h[hidx[i]], 1);
        atomicAdd(&cnt_n[nidx[i]], 1);
    }
}

// single-block exclusive scan
__global__ __launch_bounds__(256) void scan_kernel(const int* __restrict__ cnt, int* __restrict__ off, int n) {
    __shared__ int sums[256];
    int t = threadIdx.x;
    int chunk = (n + 255) / 256;
    int s = t * chunk;
    int e = min(s + chunk, n);
    int loc = 0;
    for (int i = s; i < e; i++) loc += cnt[i];
    sums[t] = loc;
    __syncthreads();
    for (int ofs = 1; ofs < 256; ofs <<= 1) {
        int v = (t >= ofs) ? sums[t - ofs] : 0;
        __syncthreads();
        sums[t] += v;
        __syncthreads();
    }
    int run = (t == 0) ? 0 : sums[t - 1];
    for (int i = s; i < e; i++) { off[i] = run; run += cnt[i]; }
    if (t == 255) off[n] = run;
}

// CSR placement via atomic cursors
__global__ void place_kernel(const int* __restrict__ nidx, const int* __restrict__ hidx,
                             const int* __restrict__ hoff, const int* __restrict__ noff,
                             int* hcur, int* ncur, int* __restrict__ hlist, int* __restrict__ nlist) {
    int e = blockIdx.x * 256 + threadIdx.x;
    if (e < N_INC) {
        int h = hidx[e], n = nidx[e];
        int p = atomicAdd(&hcur[h], 1);
        hlist[hoff[h] + p] = n;
        int q = atomicAdd(&ncur[n], 1);
        nlist[noff[n] + q] = h;
    }
}

// ---------------- weight transpose+convert: W[K,512] f32 -> Wt[512,Kpad] bf16 ----------------
__global__ void wtrans_kernel(const float* __restrict__ W, short* __restrict__ Wt, int K, int Kpad) {
    int n = blockIdx.x;
    for (int k = threadIdx.x; k < Kpad; k += 64)
        Wt[(long)n * Kpad + k] = (k < K) ? f2bf(W[(long)k * D + n]) : (short)0;
}

// plain f32 -> bf16 convert (8/thread)
__global__ void cvt_f32_bf16_kernel(const float* __restrict__ src, short* __restrict__ dst) {
    long i = ((long)blockIdx.x * 256 + threadIdx.x) * 8;
    float4 f0 = *(const float4*)(src + i);
    float4 f1 = *(const float4*)(src + i + 4);
    short8 o;
    o[0] = f2bf(f0.x); o[1] = f2bf(f0.y); o[2] = f2bf(f0.z); o[3] = f2bf(f0.w);
    o[4] = f2bf(f1.x); o[5] = f2bf(f1.y); o[6] = f2bf(f1.z); o[7] = f2bf(f1.w);
    *(short8*)(dst + i) = o;
}

// TB[4][512]: rows 0..2 = temb[r] @ W2 ; row 3 = b1 @ W2   (f32)
__global__ __launch_bounds__(256) void smallmm_kernel(
    const float* __restrict__ temb, const float* __restrict__ b1,
    const float* __restrict__ W2, float* __restrict__ TB)
{
    int col = blockIdx.x * 256 + threadIdx.x;   // grid 2 -> 512 cols
    float a0 = 0.f, a1 = 0.f, a2 = 0.f, a3 = 0.f;
    for (int j = 0; j < D; j++) {
        float w = W2[(long)j * D + col];
        a0 += temb[j] * w;
        a1 += temb[D + j] * w;
        a2 += temb[2 * D + j] * w;
        a3 += b1[j] * w;
    }
    TB[col] = a0; TB[D + col] = a1; TB[2 * D + col] = a2; TB[3 * D + col] = a3;
}

// node_features [N,49] f32 -> A0 [NPAD,64] bf16 (zero pad)
__global__ void cvt_in_kernel(const float* __restrict__ nf, short* __restrict__ A0) {
    int r = blockIdx.x;
    int c = threadIdx.x;
    short v = 0;
    if (r < N_NODES && c < D_IN) v = f2bf(nf[(long)r * D_IN + c]);
    A0[(long)r * KPAD_IN + c] = v;
}

// hedge gather (fused W2 space): h[e] = (sum_z + cnt*b1W2)/clip(cnt,1) + tembW2[type]
__global__ __launch_bounds__(256) void hedge_gather_kernel(
    const short* __restrict__ z, const int* __restrict__ hoff, const int* __restrict__ hlist,
    const int* __restrict__ htype, const float* __restrict__ TB, short* __restrict__ out)
{
    int hrow = blockIdx.x * 4 + (threadIdx.x >> 6);
    if (hrow >= N_HEDGES) return;
    int lane = threadIdx.x & 63;
    int s = hoff[hrow], e = hoff[hrow + 1];
    float acc[8] = {0, 0, 0, 0, 0, 0, 0, 0};
    for (int j = s; j < e; j++) {
        short8 v = *(const short8*)(z + (long)hlist[j] * D + lane * 8);
        #pragma unroll
        for (int k = 0; k < 8; k++) acc[k] += bf2f(v[k]);
    }
    const float cnt = (float)(e - s);
    const float inv = 1.0f / fmaxf(cnt, 1.0f);
    const float* b1p = TB + 3 * D + lane * 8;
    const float* twp = TB + (long)htype[hrow] * D + lane * 8;
    short8 o;
    #pragma unroll
    for (int k = 0; k < 8; k++)
        o[k] = f2bf((acc[k] + cnt * b1p[k]) * inv + twp[k]);
    *(short8*)(out + (long)hrow * D + lane * 8) = o;
}

// fused node gather + residual + bias + LayerNorm + GELU; x updated IN PLACE (per-row)
__global__ __launch_bounds__(256) void node_ln_gelu_kernel(
    const short* __restrict__ hmsg, const int* __restrict__ noff, const int* __restrict__ nlist,
    short* __restrict__ x, const float* __restrict__ b2,
    const float* __restrict__ g, const float* __restrict__ b, float* __restrict__ outf)
{
    const int row = blockIdx.x * 4 + (threadIdx.x >> 6);   // grid = N_NODES/4
    const int lane = threadIdx.x & 63;
    int s = noff[row], e = noff[row + 1];
    float acc[8] = {0, 0, 0, 0, 0, 0, 0, 0};
    for (int j = s; j < e; j++) {
        short8 v = *(const short8*)(hmsg + (long)nlist[j] * D + lane * 8);
        #pragma unroll
        for (int k = 0; k < 8; k++) acc[k] += bf2f(v[k]);
    }
    const float inv = 1.0f / fmaxf((float)(e - s), 1.0f);
    short8 xv = *(const short8*)(x + (long)row * D + lane * 8);
    const float4 c0 = *(const float4*)(b2 + lane * 8);
    const float4 c1 = *(const float4*)(b2 + lane * 8 + 4);
    const float cv[8] = {c0.x, c0.y, c0.z, c0.w, c1.x, c1.y, c1.z, c1.w};
    float f[8];
    float sum = 0.f, sq = 0.f;
    #pragma unroll
    for (int j = 0; j < 8; j++) {
        f[j] = acc[j] * inv + bf2f(xv[j]) + cv[j];
        sum += f[j]; sq += f[j] * f[j];
    }
    #pragma unroll
    for (int o = 32; o > 0; o >>= 1) { sum += __shfl_xor(sum, o, 64); sq += __shfl_xor(sq, o, 64); }
    const float mean = sum * (1.0f / D);
    const float var  = sq * (1.0f / D) - mean * mean;
    const float rstd = rsqrtf(var + 1e-5f);
    const float4 g0 = *(const float4*)(g + lane * 8);
    const float4 g1 = *(const float4*)(g + lane * 8 + 4);
    const float4 b0 = *(const float4*)(b + lane * 8);
    const float4 b1 = *(const float4*)(b + lane * 8 + 4);
    const float gv[8] = {g0.x, g0.y, g0.z, g0.w, g1.x, g1.y, g1.z, g1.w};
    const float bv[8] = {b0.x, b0.y, b0.z, b0.w, b1.x, b1.y, b1.z, b1.w};
    float yout[8];
    short8 o8;
    #pragma unroll
    for (int j = 0; j < 8; j++) {
        float y = (f[j] - mean) * rstd * gv[j] + bv[j];
        float gl = 0.5f * y * (1.0f + erff(y * 0.70710678118654752f));
        yout[j] = gl;
        o8[j] = f2bf(gl);
    }
    *(short8*)(x + (long)row * D + lane * 8) = o8;
    if (outf) {
        float4 o0 = {yout[0], yout[1], yout[2], yout[3]};
        float4 o1 = {yout[4], yout[5], yout[6], yout[7]};
        *(float4*)(outf + (long)row * D + lane * 8) = o0;
        *(float4*)(outf + (long)row * D + lane * 8 + 4) = o1;
    }
}

// graph pooling via sorted batch segments (bf16 in)
__global__ __launch_bounds__(64) void pool_kernel(const short* __restrict__ x, const int* __restrict__ batch,
                                                  short* __restrict__ Gbf) {
    int g = blockIdx.x;
    int lo = 0, hi = N_NODES;
    while (lo < hi) { int mid = (lo + hi) >> 1; if (batch[mid] < g) lo = mid + 1; else hi = mid; }
    int s = lo;
    hi = N_NODES;
    while (lo < hi) { int mid = (lo + hi) >> 1; if (batch[mid] < g + 1) lo = mid + 1; else hi = mid; }
    int e = lo;
    int lane = threadIdx.x;
    float acc[8] = {0, 0, 0, 0, 0, 0, 0, 0};
    for (int r = s; r < e; r++) {
        short8 v = *(const short8*)(x + (long)r * D + lane * 8);
        #pragma unroll
        for (int k = 0; k < 8; k++) acc[k] += bf2f(v[k]);
    }
    float inv = 1.0f / fmaxf((float)(e - s), 1.0f);
    short8 o;
    #pragma unroll
    for (int k = 0; k < 8; k++) o[k] = f2bf(acc[k] * inv);
    *(short8*)(Gbf + (long)g * D + lane * 8) = o;
}

__global__ void batchf_kernel(const int* __restrict__ batch, float* __restrict__ ob) {
    int i = blockIdx.x * 256 + threadIdx.x;
    if (i < N_NODES) ob[i] = (float)batch[i];
}

extern "C" void kernel_launch(void* const* d_in, const int* in_sizes, int n_in,
                              void* d_out, int out_size, void* d_ws, size_t ws_size,
                              hipStream_t stream) {
    (void)in_sizes; (void)n_in; (void)out_size; (void)ws_size;
    const float* nf    = (const float*)d_in[0];
    const int*   nidx  = (const int*)d_in[1];
    const int*   hidx  = (const int*)d_in[2];
    const int*   htype = (const int*)d_in[3];
    const int*   batch = (const int*)d_in[4];
    const float* in_w  = (const float*)d_in[6];
    const float* in_b  = (const float*)d_in[7];
    const float* temb  = (const float*)d_in[8];
    const float* l1w   = (const float*)d_in[9];
    const float* l1b   = (const float*)d_in[10];
    const float* l2w   = (const float*)d_in[11];
    const float* l2b   = (const float*)d_in[12];
    const float* lng   = (const float*)d_in[13];
    const float* lnb   = (const float*)d_in[14];
    const float* outw  = (const float*)d_in[15];
    const float* outb  = (const float*)d_in[16];

    float* out_graph = (float*)d_out;                       // [1024,512]
    float* out_nodes = out_graph + (long)N_GRAPHS * D;      // [100000,512]
    float* out_batch = out_nodes + (long)N_NODES * D;       // [100000]

    char* wsb = (char*)d_ws;
    size_t off = 0;
    auto alloc = [&](size_t bytes) {
        void* p = wsb + off;
        off += (bytes + 255) & ~(size_t)255;
        return p;
    };
    short* x_bf  = (short*)alloc((size_t)NPAD * D * 2);
    short* z_bf  = (short*)alloc((size_t)NPAD * D * 2);
    short* h_bf  = (short*)alloc((size_t)N_HEDGES * D * 2);
    short* G_bf  = (short*)alloc((size_t)N_GRAPHS * D * 2);
    short* A0    = (short*)alloc((size_t)NPAD * KPAD_IN * 2);
    short* wt    = (short*)alloc((size_t)D * D * 2);
    short* w1bf  = (short*)alloc((size_t)D * D * 2);
    short* W12t  = (short*)alloc((size_t)3 * D * D * 2);
    float* TB    = (float*)alloc((size_t)3 * 4 * D * 4);
    int* cnt_h   = (int*)alloc((size_t)N_HEDGES * 4);
    int* cnt_n   = (int*)alloc((size_t)N_NODES * 4);
    int* hoff    = (int*)alloc((size_t)(N_HEDGES + 1) * 4);
    int* noff    = (int*)alloc((size_t)(N_NODES + 1) * 4);
    int* hcur    = (int*)alloc((size_t)N_HEDGES * 4);
    int* ncur    = (int*)alloc((size_t)N_NODES * 4);
    int* hlist   = (int*)alloc((size_t)N_INC * 4);
    int* nlist   = (int*)alloc((size_t)N_INC * 4);

    // ---- build CSR (both directions) ----
    hipMemsetAsync(cnt_h, 0, (size_t)N_HEDGES * 4, stream);
    hipMemsetAsync(cnt_n, 0, (size_t)N_NODES * 4, stream);
    hipMemsetAsync(hcur,  0, (size_t)N_HEDGES * 4, stream);
    hipMemsetAsync(ncur,  0, (size_t)N_NODES * 4, stream);
    count_inc_kernel<<<(N_INC + 255) / 256, 256, 0, stream>>>(nidx, hidx, cnt_n, cnt_h);
    scan_kernel<<<1, 256, 0, stream>>>(cnt_h, hoff, N_HEDGES);
    scan_kernel<<<1, 256, 0, stream>>>(cnt_n, noff, N_NODES);
    place_kernel<<<(N_INC + 255) / 256, 256, 0, stream>>>(nidx, hidx, hoff, noff, hcur, ncur, hlist, nlist);
    batchf_kernel<<<(N_NODES + 255) / 256, 256, 0, stream>>>(batch, out_batch);

    // ---- per-layer weight precompute: W12t[i] = (l1_w[i] @ l2_w[i])^T packed as Bt; TB[i] rows ----
    for (int i = 0; i < 3; i++) {
        cvt_f32_bf16_kernel<<<(D * D / 8) / 256, 256, 0, stream>>>(l1w + (size_t)i * D * D, w1bf);
        wtrans_kernel<<<D, 64, 0, stream>>>(l2w + (size_t)i * D * D, wt, D, D);
        gemm_bf16<<<(D / 128) * 4, 256, 0, stream>>>(w1bf, wt, nullptr, nullptr,
                                                     nullptr, nullptr, W12t + (size_t)i * D * D, D, 4);
        smallmm_kernel<<<2, 256, 0, stream>>>(temb, l1b + (size_t)i * D,
                                              l2w + (size_t)i * D * D, TB + (size_t)i * 4 * D);
    }

    // ---- input projection: x_bf = bf16(nf @ in_w + in_b) ----
    wtrans_kernel<<<D, 64, 0, stream>>>(in_w, wt, D_IN, KPAD_IN);
    cvt_in_kernel<<<NPAD, 64, 0, stream>>>(nf, A0);
    const int NWG = (NPAD / 128) * 4;   // 3128
    gemm_bf16<<<NWG, 256, 0, stream>>>(A0, wt, in_b, nullptr, x_bf, nullptr, nullptr, KPAD_IN, 4);

    for (int i = 0; i < 3; i++) {
        // z = x @ W12[i]   (one big GEMM per layer)
        gemm_bf16<<<NWG, 256, 0, stream>>>(x_bf, W12t + (size_t)i * D * D, nullptr, nullptr,
                                           z_bf, nullptr, nullptr, D, 4);
        // h = (segsum(z) + cnt*b1W2)/clip + tembW2[type]
        hedge_gather_kernel<<<(N_HEDGES + 3) / 4, 256, 0, stream>>>(z_bf, hoff, hlist, htype,
                                                                    TB + (size_t)i * 4 * D, h_bf);
        // x = gelu(LN(segsum(h)/clip + x + b2))   (in place; last layer also writes f32)
        node_ln_gelu_kernel<<<N_NODES / 4, 256, 0, stream>>>(h_bf, noff, nlist, x_bf,
                                                             l2b + (size_t)i * D,
                                                             lng + (size_t)i * D, lnb + (size_t)i * D,
                                                             (i < 2) ? nullptr : out_nodes);
    }

    // ---- graph pooling + output projection ----
    pool_kernel<<<N_GRAPHS, 64, 0, stream>>>(x_bf, batch, G_bf);
    wtrans_kernel<<<D, 64, 0, stream>>>(outw, wt, D, D);
    gemm_bf16<<<(N_GRAPHS / 128) * 4, 256, 0, stream>>>(G_bf, wt, outb, nullptr,
                                                        nullptr, out_graph, nullptr, D, 4);
}

// Round 9
// 1139.323 us; speedup vs baseline: 1.9779x; 1.1942x over previous
//
#include <hip/hip_runtime.h>
#include <math.h>

#define N_NODES  100000
#define N_HEDGES 50000
#define N_INC    300000
#define N_GRAPHS 1024
#define D_IN     49
#define D        512
#define NPAD     100096   // 782 * 128
#define KPAD_IN  64

typedef __attribute__((ext_vector_type(8))) short short8;
typedef __attribute__((ext_vector_type(8))) __bf16 bf16x8;
typedef __attribute__((ext_vector_type(4))) float f32x4;

__device__ __forceinline__ short f2bf(float f) {
    union { float f; unsigned u; } v; v.f = f;
    unsigned r = v.u + 0x7fffu + ((v.u >> 16) & 1u);
    return (short)(r >> 16);
}
__device__ __forceinline__ float bf2f(short s) {
    union { unsigned u; float f; } v; v.u = ((unsigned)(unsigned short)s) << 16;
    return v.f;
}

__device__ __forceinline__ void gld16(const void* g, void* l) {
    __builtin_amdgcn_global_load_lds(
        (const __attribute__((address_space(1))) unsigned int*)g,
        (__attribute__((address_space(3))) unsigned int*)l, 16, 0, 0);
}

// ---------------- GEMM: C[M,512] = A[M,K](bf16) @ Bt[512,K](bf16) (+bias) (+resid_bf16) --------------
// 128x128 tile, 4 waves. global_load_lds(16B) staging, pre-swizzled source (conflict-free ds_read).
// Double-buffered, one __syncthreads per 32-K step. Builtin MFMA.
// Outputs: Cbf (bf16 row-major), Cf (f32 row-major), CbfT (bf16 TRANSPOSED, stride strideT, rows<strideT).
__global__ __launch_bounds__(256) void gemm_bf16(
    const short* __restrict__ A, const short* __restrict__ Bt,
    const float* __restrict__ bias, const short* __restrict__ residbf,
    short* __restrict__ Cbf, float* __restrict__ Cf, short* __restrict__ CbfT,
    int strideT, int K, int nby)
{
    __shared__ short As[2][128][32];
    __shared__ short Bs[2][128][32];
    const int tid  = threadIdx.x;
    const int lane = tid & 63;
    const int wave = tid >> 6;
    const int wr = wave >> 1, wc = wave & 1;

    // bijective XCD-aware swizzle (m204)
    const int nwg = gridDim.x;
    const int q8 = nwg >> 3, r8 = nwg & 7;
    const int xcd = blockIdx.x & 7, loc = blockIdx.x >> 3;
    const int wg = (xcd < r8) ? (xcd * (q8 + 1) + loc) : (r8 * (q8 + 1) + (xcd - r8) * q8 + loc);
    const long row0 = (long)(wg / nby) * 128;
    const int  col0 = (wg % nby) * 128;

    f32x4 acc[4][4];
    #pragma unroll
    for (int m = 0; m < 4; m++)
        #pragma unroll
        for (int n = 0; n < 4; n++)
            acc[m][n] = (f32x4)(0.0f);

    const int ch   = lane & 3;
    const int rofs = lane >> 2;
    const short* aSrc[2];
    const short* bSrc[2];
    #pragma unroll
    for (int j = 0; j < 2; j++) {
        const int q = wave * 2 + j;
        const int rloc = q * 16 + rofs;
        const int sw = (rloc >> 1) & 3;
        aSrc[j] = A  + (row0 + rloc) * (long)K + (ch ^ sw) * 8;
        bSrc[j] = Bt + ((long)col0 + rloc) * K + (ch ^ sw) * 8;
    }

    const int ks = lane >> 4;
    const int rl = lane & 15;
    const int nk = K >> 5;

    #pragma unroll
    for (int j = 0; j < 2; j++) {
        const int q = wave * 2 + j;
        gld16(aSrc[j], &As[0][q * 16][0]);
        gld16(bSrc[j], &Bs[0][q * 16][0]);
    }
    __syncthreads();

    int cur = 0;
    for (int t = 0; t < nk; t++) {
        if (t + 1 < nk) {
            const int nxt = cur ^ 1;
            #pragma unroll
            for (int j = 0; j < 2; j++) {
                const int q = wave * 2 + j;
                gld16(aSrc[j] + (t + 1) * 32, &As[nxt][q * 16][0]);
                gld16(bSrc[j] + (t + 1) * 32, &Bs[nxt][q * 16][0]);
            }
        }
        bf16x8 a[4], b[4];
        #pragma unroll
        for (int m = 0; m < 4; m++) {
            const int rr = wr * 64 + m * 16 + rl;
            a[m] = *(const bf16x8*)&As[cur][rr][(ks ^ ((rr >> 1) & 3)) * 8];
        }
        #pragma unroll
        for (int n = 0; n < 4; n++) {
            const int rr = wc * 64 + n * 16 + rl;
            b[n] = *(const bf16x8*)&Bs[cur][rr][(ks ^ ((rr >> 1) & 3)) * 8];
        }
        #pragma unroll
        for (int m = 0; m < 4; m++)
            #pragma unroll
            for (int n = 0; n < 4; n++)
                acc[m][n] = __builtin_amdgcn_mfma_f32_16x16x32_bf16(a[m], b[n], acc[m][n], 0, 0, 0);
        __syncthreads();
        cur ^= 1;
    }

    const int rl2 = lane & 15;
    const int rb4 = wr * 64 + (lane >> 4) * 4;
    #pragma unroll
    for (int m = 0; m < 4; m++) {
        #pragma unroll
        for (int n = 0; n < 4; n++) {
            const int col = col0 + wc * 64 + n * 16 + rl2;
            const float bi = bias ? bias[col] : 0.0f;
            #pragma unroll
            for (int rr = 0; rr < 4; rr++) {
                const long row = row0 + rb4 + m * 16 + rr;
                float v = acc[m][n][rr] + bi;
                if (residbf) v += bf2f(residbf[row * D + col]);
                if (Cbf)  Cbf[row * D + col] = f2bf(v);
                if (Cf)   Cf[row * D + col]  = v;
                if (CbfT && row < strideT) CbfT[(long)col * strideT + row] = f2bf(v);
            }
        }
    }
}

// ---------------- degree counts ----------------
__global__ void count_inc_kernel(const int* __restrict__ nidx, const int* __restrict__ hidx,
                                 int* cnt_n, int* cnt_h) {
    int i = blockIdx.x * 256 + threadIdx.x;
    if (i < N_INC) {
        atomicAdd(&cnt_h[hidx[i]], 1);
        atomicAdd(&cnt_n[nidx[i]], 1);
    }
}

// ---------------- hierarchical exclusive scan (3 phases, 2048 elems/block) ----------------
__global__ __launch_bounds__(256) void scan1_kernel(const int* __restrict__ cnt, int* __restrict__ out,
                                                    int* __restrict__ bsum, int n) {
    __shared__ int s[256];
    const int t = threadIdx.x;
    const long base = (long)blockIdx.x * 2048 + t * 8;
    int v[8];
    int ts = 0;
    #pragma unroll
    for (int j = 0; j < 8; j++) {
        v[j] = (base + j < n) ? cnt[base + j] : 0;
        ts += v[j];
    }
    s[t] = ts;
    __syncthreads();
    for (int ofs = 1; ofs < 256; ofs <<= 1) {
        int x = (t >= ofs) ? s[t - ofs] : 0;
        __syncthreads();
        s[t] += x;
        __syncthreads();
    }
    int run = (t == 0) ? 0 : s[t - 1];
    #pragma unroll
    for (int j = 0; j < 8; j++) {
        if (base + j < n) out[base + j] = run;
        run += v[j];
    }
    if (t == 255) bsum[blockIdx.x] = s[255];
}

__global__ __launch_bounds__(256) void scan2_kernel(int* __restrict__ bsum, int nb, int* __restrict__ total) {
    __shared__ int s[256];
    const int t = threadIdx.x;
    int v = (t < nb) ? bsum[t] : 0;
    s[t] = v;
    __syncthreads();
    for (int ofs = 1; ofs < 256; ofs <<= 1) {
        int x = (t >= ofs) ? s[t - ofs] : 0;
        __syncthreads();
        s[t] += x;
        __syncthreads();
    }
    if (t < nb) bsum[t] = (t == 0) ? 0 : s[t - 1];
    if (t == 255) *total = s[255];
}

__global__ __launch_bounds__(256) void scan3_kernel(int* __restrict__ out, const int* __restrict__ bsum, int n) {
    const int add = bsum[blockIdx.x];
    if (add == 0) return;
    const long base = (long)blockIdx.x * 2048 + threadIdx.x * 8;
    #pragma unroll
    for (int j = 0; j < 8; j++)
        if (base + j < n) out[base + j] += add;
}

// CSR placement via atomic cursors
__global__ void place_kernel(const int* __restrict__ nidx, const int* __restrict__ hidx,
                             const int* __restrict__ hoff, const int* __restrict__ noff,
                             int* hcur, int* ncur, int* __restrict__ hlist, int* __restrict__ nlist) {
    int e = blockIdx.x * 256 + threadIdx.x;
    if (e < N_INC) {
        int h = hidx[e], n = nidx[e];
        int p = atomicAdd(&hcur[h], 1);
        hlist[hoff[h] + p] = n;
        int q = atomicAdd(&ncur[n], 1);
        nlist[noff[n] + q] = h;
    }
}

// ---------------- weight transpose+convert: W[K,512] f32 -> Wt[512,Kpad] bf16 ----------------
__global__ void wtrans_kernel(const float* __restrict__ W, short* __restrict__ Wt, int K, int Kpad) {
    int n = blockIdx.x;
    for (int k = threadIdx.x; k < Kpad; k += 64)
        Wt[(long)n * Kpad + k] = (k < K) ? f2bf(W[(long)k * D + n]) : (short)0;
}

// plain f32 -> bf16 convert (8/thread)
__global__ void cvt_f32_bf16_kernel(const float* __restrict__ src, short* __restrict__ dst) {
    long i = ((long)blockIdx.x * 256 + threadIdx.x) * 8;
    float4 f0 = *(const float4*)(src + i);
    float4 f1 = *(const float4*)(src + i + 4);
    short8 o;
    o[0] = f2bf(f0.x); o[1] = f2bf(f0.y); o[2] = f2bf(f0.z); o[3] = f2bf(f0.w);
    o[4] = f2bf(f1.x); o[5] = f2bf(f1.y); o[6] = f2bf(f1.z); o[7] = f2bf(f1.w);
    *(short8*)(dst + i) = o;
}

// W[rows,512] f32 -> dst[128,512] bf16, zero-padding rows >= rows_real
__global__ void cvt_w_pad_kernel(const float* __restrict__ src, short* __restrict__ dst, int rows_real) {
    int r = blockIdx.x;           // 0..127
    int c = threadIdx.x * 8;      // 64 threads
    short8 o = (short8)0;
    if (r < rows_real) {
        float4 f0 = *(const float4*)(src + (long)r * D + c);
        float4 f1 = *(const float4*)(src + (long)r * D + c + 4);
        o[0] = f2bf(f0.x); o[1] = f2bf(f0.y); o[2] = f2bf(f0.z); o[3] = f2bf(f0.w);
        o[4] = f2bf(f1.x); o[5] = f2bf(f1.y); o[6] = f2bf(f1.z); o[7] = f2bf(f1.w);
    }
    *(short8*)(dst + (long)r * D + c) = o;
}

// vecmat: out[col] = sum_j v[j] * M[j*512+col]   (f32; grid 2 x 256)
__global__ __launch_bounds__(256) void vecmat_kernel(const float* __restrict__ v,
                                                     const float* __restrict__ M,
                                                     float* __restrict__ out) {
    int col = blockIdx.x * 256 + threadIdx.x;
    float a = 0.f;
    for (int j = 0; j < D; j++) a += v[j] * M[(long)j * D + col];
    out[col] = a;
}

// TB[4][512]: rows 0..2 = temb[r] @ W2 ; row 3 = b1 @ W2   (f32)
__global__ __launch_bounds__(256) void smallmm_kernel(
    const float* __restrict__ temb, const float* __restrict__ b1,
    const float* __restrict__ W2, float* __restrict__ TB)
{
    int col = blockIdx.x * 256 + threadIdx.x;
    float a0 = 0.f, a1 = 0.f, a2 = 0.f, a3 = 0.f;
    for (int j = 0; j < D; j++) {
        float w = W2[(long)j * D + col];
        a0 += temb[j] * w;
        a1 += temb[D + j] * w;
        a2 += temb[2 * D + j] * w;
        a3 += b1[j] * w;
    }
    TB[col] = a0; TB[D + col] = a1; TB[2 * D + col] = a2; TB[3 * D + col] = a3;
}

// node_features [N,49] f32 -> A0 [NPAD,64] bf16 (zero pad)
__global__ void cvt_in_kernel(const float* __restrict__ nf, short* __restrict__ A0) {
    int r = blockIdx.x;
    int c = threadIdx.x;
    short v = 0;
    if (r < N_NODES && c < D_IN) v = f2bf(nf[(long)r * D_IN + c]);
    A0[(long)r * KPAD_IN + c] = v;
}

// hedge gather (fused W2 space): h[e] = (sum_z + cnt*b1W2)/clip(cnt,1) + tembW2[type]
__global__ __launch_bounds__(256) void hedge_gather_kernel(
    const short* __restrict__ z, const int* __restrict__ hoff, const int* __restrict__ hlist,
    const int* __restrict__ htype, const float* __restrict__ TB, short* __restrict__ out)
{
    int hrow = blockIdx.x * 4 + (threadIdx.x >> 6);
    if (hrow >= N_HEDGES) return;
    int lane = threadIdx.x & 63;
    int s = hoff[hrow], e = hoff[hrow + 1];
    float acc[8] = {0, 0, 0, 0, 0, 0, 0, 0};
    for (int j = s; j < e; j++) {
        short8 v = *(const short8*)(z + (long)hlist[j] * D + lane * 8);
        #pragma unroll
        for (int k = 0; k < 8; k++) acc[k] += bf2f(v[k]);
    }
    const float cnt = (float)(e - s);
    const float inv = 1.0f / fmaxf(cnt, 1.0f);
    const float* b1p = TB + 3 * D + lane * 8;
    const float* twp = TB + (long)htype[hrow] * D + lane * 8;
    short8 o;
    #pragma unroll
    for (int k = 0; k < 8; k++)
        o[k] = f2bf((acc[k] + cnt * b1p[k]) * inv + twp[k]);
    *(short8*)(out + (long)hrow * D + lane * 8) = o;
}

// fused node gather + residual + bias + LayerNorm + GELU; x updated IN PLACE (per-row)
__global__ __launch_bounds__(256) void node_ln_gelu_kernel(
    const short* __restrict__ hmsg, const int* __restrict__ noff, const int* __restrict__ nlist,
    short* __restrict__ x, const float* __restrict__ b2,
    const float* __restrict__ g, const float* __restrict__ b, float* __restrict__ outf)
{
    const int row = blockIdx.x * 4 + (threadIdx.x >> 6);
    const int lane = threadIdx.x & 63;
    int s = noff[row], e = noff[row + 1];
    float acc[8] = {0, 0, 0, 0, 0, 0, 0, 0};
    for (int j = s; j < e; j++) {
        short8 v = *(const short8*)(hmsg + (long)nlist[j] * D + lane * 8);
        #pragma unroll
        for (int k = 0; k < 8; k++) acc[k] += bf2f(v[k]);
    }
    const float inv = 1.0f / fmaxf((float)(e - s), 1.0f);
    short8 xv = *(const short8*)(x + (long)row * D + lane * 8);
    const float4 c0 = *(const float4*)(b2 + lane * 8);
    const float4 c1 = *(const float4*)(b2 + lane * 8 + 4);
    const float cv[8] = {c0.x, c0.y, c0.z, c0.w, c1.x, c1.y, c1.z, c1.w};
    float f[8];
    float sum = 0.f, sq = 0.f;
    #pragma unroll
    for (int j = 0; j < 8; j++) {
        f[j] = acc[j] * inv + bf2f(xv[j]) + cv[j];
        sum += f[j]; sq += f[j] * f[j];
    }
    #pragma unroll
    for (int o = 32; o > 0; o >>= 1) { sum += __shfl_xor(sum, o, 64); sq += __shfl_xor(sq, o, 64); }
    const float mean = sum * (1.0f / D);
    const float var  = sq * (1.0f / D) - mean * mean;
    const float rstd = rsqrtf(var + 1e-5f);
    const float4 g0 = *(const float4*)(g + lane * 8);
    const float4 g1 = *(const float4*)(g + lane * 8 + 4);
    const float4 b0 = *(const float4*)(b + lane * 8);
    const float4 b1 = *(const float4*)(b + lane * 8 + 4);
    const float gv[8] = {g0.x, g0.y, g0.z, g0.w, g1.x, g1.y, g1.z, g1.w};
    const float bv[8] = {b0.x, b0.y, b0.z, b0.w, b1.x, b1.y, b1.z, b1.w};
    float yout[8];
    short8 o8;
    #pragma unroll
    for (int j = 0; j < 8; j++) {
        float y = (f[j] - mean) * rstd * gv[j] + bv[j];
        float gl = 0.5f * y * (1.0f + erff(y * 0.70710678118654752f));
        yout[j] = gl;
        o8[j] = f2bf(gl);
    }
    *(short8*)(x + (long)row * D + lane * 8) = o8;
    if (outf) {
        float4 o0 = {yout[0], yout[1], yout[2], yout[3]};
        float4 o1 = {yout[4], yout[5], yout[6], yout[7]};
        *(float4*)(outf + (long)row * D + lane * 8) = o0;
        *(float4*)(outf + (long)row * D + lane * 8 + 4) = o1;
    }
}

// graph pooling via sorted batch segments (bf16 in)
__global__ __launch_bounds__(64) void pool_kernel(const short* __restrict__ x, const int* __restrict__ batch,
                                                  short* __restrict__ Gbf) {
    int g = blockIdx.x;
    int lo = 0, hi = N_NODES;
    while (lo < hi) { int mid = (lo + hi) >> 1; if (batch[mid] < g) lo = mid + 1; else hi = mid; }
    int s = lo;
    hi = N_NODES;
    while (lo < hi) { int mid = (lo + hi) >> 1; if (batch[mid] < g + 1) lo = mid + 1; else hi = mid; }
    int e = lo;
    int lane = threadIdx.x;
    float acc[8] = {0, 0, 0, 0, 0, 0, 0, 0};
    for (int r = s; r < e; r++) {
        short8 v = *(const short8*)(x + (long)r * D + lane * 8);
        #pragma unroll
        for (int k = 0; k < 8; k++) acc[k] += bf2f(v[k]);
    }
    float inv = 1.0f / fmaxf((float)(e - s), 1.0f);
    short8 o;
    #pragma unroll
    for (int k = 0; k < 8; k++) o[k] = f2bf(acc[k] * inv);
    *(short8*)(Gbf + (long)g * D + lane * 8) = o;
}

__global__ void batchf_kernel(const int* __restrict__ batch, float* __restrict__ ob) {
    int i = blockIdx.x * 256 + threadIdx.x;
    if (i < N_NODES) ob[i] = (float)batch[i];
}

extern "C" void kernel_launch(void* const* d_in, const int* in_sizes, int n_in,
                              void* d_out, int out_size, void* d_ws, size_t ws_size,
                              hipStream_t stream) {
    (void)in_sizes; (void)n_in; (void)out_size; (void)ws_size;
    const float* nf    = (const float*)d_in[0];
    const int*   nidx  = (const int*)d_in[1];
    const int*   hidx  = (const int*)d_in[2];
    const int*   htype = (const int*)d_in[3];
    const int*   batch = (const int*)d_in[4];
    const float* in_w  = (const float*)d_in[6];
    const float* in_b  = (const float*)d_in[7];
    const float* temb  = (const float*)d_in[8];
    const float* l1w   = (const float*)d_in[9];
    const float* l1b   = (const float*)d_in[10];
    const float* l2w   = (const float*)d_in[11];
    const float* l2b   = (const float*)d_in[12];
    const float* lng   = (const float*)d_in[13];
    const float* lnb   = (const float*)d_in[14];
    const float* outw  = (const float*)d_in[15];
    const float* outb  = (const float*)d_in[16];

    float* out_graph = (float*)d_out;                       // [1024,512]
    float* out_nodes = out_graph + (long)N_GRAPHS * D;      // [100000,512]
    float* out_batch = out_nodes + (long)N_NODES * D;       // [100000]

    char* wsb = (char*)d_ws;
    size_t off = 0;
    auto alloc = [&](size_t bytes) {
        void* p = wsb + off;
        off += (bytes + 255) & ~(size_t)255;
        return p;
    };
    short* x_bf  = (short*)alloc((size_t)NPAD * D * 2);
    short* z_bf  = (short*)alloc((size_t)NPAD * D * 2);
    short* h_bf  = (short*)alloc((size_t)N_HEDGES * D * 2);
    short* G_bf  = (short*)alloc((size_t)N_GRAPHS * D * 2);
    short* A0    = (short*)alloc((size_t)NPAD * KPAD_IN * 2);
    short* wt    = (short*)alloc((size_t)D * D * 2);
    short* w1bf  = (short*)alloc((size_t)D * D * 2);
    short* W12t  = (short*)alloc((size_t)3 * D * D * 2);
    short* inwbf = (short*)alloc((size_t)128 * D * 2);
    short* M0t   = (short*)alloc((size_t)D * KPAD_IN * 2);
    float* TB    = (float*)alloc((size_t)3 * 4 * D * 4);
    float* tmpv  = (float*)alloc((size_t)D * 4);
    float* bias0 = (float*)alloc((size_t)D * 4);
    int* cnt_h   = (int*)alloc((size_t)N_HEDGES * 4);
    int* cnt_n   = (int*)alloc((size_t)N_NODES * 4);
    int* hoff    = (int*)alloc((size_t)(N_HEDGES + 1) * 4);
    int* noff    = (int*)alloc((size_t)(N_NODES + 1) * 4);
    int* hcur    = (int*)alloc((size_t)N_HEDGES * 4);
    int* ncur    = (int*)alloc((size_t)N_NODES * 4);
    int* hlist   = (int*)alloc((size_t)N_INC * 4);
    int* nlist   = (int*)alloc((size_t)N_INC * 4);
    int* bsum    = (int*)alloc((size_t)256 * 4);

    // ---- build CSR (both directions) ----
    hipMemsetAsync(cnt_h, 0, (size_t)N_HEDGES * 4, stream);
    hipMemsetAsync(cnt_n, 0, (size_t)N_NODES * 4, stream);
    hipMemsetAsync(hcur,  0, (size_t)N_HEDGES * 4, stream);
    hipMemsetAsync(ncur,  0, (size_t)N_NODES * 4, stream);
    count_inc_kernel<<<(N_INC + 255) / 256, 256, 0, stream>>>(nidx, hidx, cnt_n, cnt_h);
    const int NBH = (N_HEDGES + 2047) / 2048;   // 25
    const int NBN = (N_NODES + 2047) / 2048;    // 49
    scan1_kernel<<<NBH, 256, 0, stream>>>(cnt_h, hoff, bsum, N_HEDGES);
    scan2_kernel<<<1, 256, 0, stream>>>(bsum, NBH, hoff + N_HEDGES);
    scan3_kernel<<<NBH, 256, 0, stream>>>(hoff, bsum, N_HEDGES);
    scan1_kernel<<<NBN, 256, 0, stream>>>(cnt_n, noff, bsum, N_NODES);
    scan2_kernel<<<1, 256, 0, stream>>>(bsum, NBN, noff + N_NODES);
    scan3_kernel<<<NBN, 256, 0, stream>>>(noff, bsum, N_NODES);
    place_kernel<<<(N_INC + 255) / 256, 256, 0, stream>>>(nidx, hidx, hoff, noff, hcur, ncur, hlist, nlist);
    batchf_kernel<<<(N_NODES + 255) / 256, 256, 0, stream>>>(batch, out_batch);

    // ---- per-layer weight precompute: W12t[i] = (l1_w[i] @ l2_w[i])^T packed as Bt; TB[i] rows ----
    for (int i = 0; i < 3; i++) {
        cvt_f32_bf16_kernel<<<(D * D / 8) / 256, 256, 0, stream>>>(l1w + (size_t)i * D * D, w1bf);
        wtrans_kernel<<<D, 64, 0, stream>>>(l2w + (size_t)i * D * D, wt, D, D);
        gemm_bf16<<<(D / 128) * 4, 256, 0, stream>>>(w1bf, wt, nullptr, nullptr,
                                                     nullptr, nullptr, W12t + (size_t)i * D * D,
                                                     D, D, 4);
        smallmm_kernel<<<2, 256, 0, stream>>>(temb, l1b + (size_t)i * D,
                                              l2w + (size_t)i * D * D, TB + (size_t)i * 4 * D);
    }

    // ---- layer-0 shortcut: M0t = (in_w @ W12[0])^T (K=64-packed), bias0 = (in_b@l1w0)@l2w0 ----
    cvt_w_pad_kernel<<<128, 64, 0, stream>>>(in_w, inwbf, D_IN);
    gemm_bf16<<<(128 / 128) * 4, 256, 0, stream>>>(inwbf, W12t, nullptr, nullptr,
                                                   nullptr, nullptr, M0t, KPAD_IN, D, 4);
    vecmat_kernel<<<2, 256, 0, stream>>>(in_b, l1w, tmpv);
    vecmat_kernel<<<2, 256, 0, stream>>>(tmpv, l2w, bias0);

    // ---- input projection: x_bf = bf16(nf @ in_w + in_b) ----
    wtrans_kernel<<<D, 64, 0, stream>>>(in_w, wt, D_IN, KPAD_IN);
    cvt_in_kernel<<<NPAD, 64, 0, stream>>>(nf, A0);
    const int NWG = (NPAD / 128) * 4;   // 3128
    gemm_bf16<<<NWG, 256, 0, stream>>>(A0, wt, in_b, nullptr, x_bf, nullptr, nullptr, 0, KPAD_IN, 4);

    for (int i = 0; i < 3; i++) {
        // z = x @ W12[i]; layer 0 uses the K=64 shortcut z0 = A0 @ M0 + bias0
        if (i == 0)
            gemm_bf16<<<NWG, 256, 0, stream>>>(A0, M0t, bias0, nullptr,
                                               z_bf, nullptr, nullptr, 0, KPAD_IN, 4);
        else
            gemm_bf16<<<NWG, 256, 0, stream>>>(x_bf, W12t + (size_t)i * D * D, nullptr, nullptr,
                                               z_bf, nullptr, nullptr, 0, D, 4);
        // h = (segsum(z) + cnt*b1W2)/clip + tembW2[type]
        hedge_gather_kernel<<<(N_HEDGES + 3) / 4, 256, 0, stream>>>(z_bf, hoff, hlist, htype,
                                                                    TB + (size_t)i * 4 * D, h_bf);
        // x = gelu(LN(segsum(h)/clip + x + b2))   (in place; last layer also writes f32)
        node_ln_gelu_kernel<<<N_NODES / 4, 256, 0, stream>>>(h_bf, noff, nlist, x_bf,
                                                             l2b + (size_t)i * D,
                                                             lng + (size_t)i * D, lnb + (size_t)i * D,
                                                             (i < 2) ? nullptr : out_nodes);
    }

    // ---- graph pooling + output projection ----
    pool_kernel<<<N_GRAPHS, 64, 0, stream>>>(x_bf, batch, G_bf);
    wtrans_kernel<<<D, 64, 0, stream>>>(outw, wt, D, D);
    gemm_bf16<<<(N_GRAPHS / 128) * 4, 256, 0, stream>>>(G_bf, wt, outb, nullptr,
                                                        nullptr, out_graph, nullptr, 0, D, 4);
}